// Round 1
// baseline (917.346 us; speedup 1.0000x reference)
//
#include <hip/hip_runtime.h>
#include <cstddef>
#include <cstdint>

namespace {

constexpr int S = 48;
constexpr int N = S * S;        // 2304 positions
constexpr int D = 512;          // d_model
constexpr int DK = 64;          // head dim
constexpr int H = 8;
constexpr int B = 2;
constexpr int BH = B * H;       // 16
constexpr float SCALE = 0.125f;     // 1/sqrt(DK)
constexpr float INV2S2 = 0.02f;     // 1/(2*sigma^2), sigma=5

// ---------------------------------------------------------------------------
// Kernel A: fused Q/K projection.  out[m,n] = sum_k X[m,k]*W[n,k] + bias[n]
// M=4608 rows, N=512, K=512.  64x64 tile, BK=16, 256 threads, 4x4 per thread.
// ---------------------------------------------------------------------------
__global__ __launch_bounds__(256)
void proj_kernel(const float* __restrict__ qin, const float* __restrict__ kin,
                 const float* __restrict__ Wq, const float* __restrict__ bq,
                 const float* __restrict__ Wk, const float* __restrict__ bk,
                 float* __restrict__ Qo, float* __restrict__ Ko)
{
    const float* X; const float* W; const float* bias; float* out;
    if (blockIdx.z == 0) { X = qin; W = Wq; bias = bq; out = Qo; }
    else                 { X = kin; W = Wk; bias = bk; out = Ko; }

    __shared__ alignas(16) float As[16][68];
    __shared__ alignas(16) float Ws[16][68];

    const int tx = threadIdx.x, ty = threadIdx.y;
    const int tid = ty * 16 + tx;
    const int m0 = blockIdx.y * 64;
    const int n0 = blockIdx.x * 64;
    const int lr = tid >> 2;          // 0..63 (tile row)
    const int lc = (tid & 3) << 2;    // 0,4,8,12 (k-col)

    float acc[4][4] = {};

    for (int k0 = 0; k0 < D; k0 += 16) {
        float4 av = *(const float4*)(X + (size_t)(m0 + lr) * D + k0 + lc);
        float4 wv = *(const float4*)(W + (size_t)(n0 + lr) * D + k0 + lc);
        As[lc+0][lr] = av.x; As[lc+1][lr] = av.y; As[lc+2][lr] = av.z; As[lc+3][lr] = av.w;
        Ws[lc+0][lr] = wv.x; Ws[lc+1][lr] = wv.y; Ws[lc+2][lr] = wv.z; Ws[lc+3][lr] = wv.w;
        __syncthreads();
        #pragma unroll
        for (int kk = 0; kk < 16; kk++) {
            float4 a  = *(const float4*)&As[kk][4*ty];
            float4 w4 = *(const float4*)&Ws[kk][4*tx];
            acc[0][0] += a.x*w4.x; acc[0][1] += a.x*w4.y; acc[0][2] += a.x*w4.z; acc[0][3] += a.x*w4.w;
            acc[1][0] += a.y*w4.x; acc[1][1] += a.y*w4.y; acc[1][2] += a.y*w4.z; acc[1][3] += a.y*w4.w;
            acc[2][0] += a.z*w4.x; acc[2][1] += a.z*w4.y; acc[2][2] += a.z*w4.z; acc[2][3] += a.z*w4.w;
            acc[3][0] += a.w*w4.x; acc[3][1] += a.w*w4.y; acc[3][2] += a.w*w4.z; acc[3][3] += a.w*w4.w;
        }
        __syncthreads();
    }
    float4 bv = *(const float4*)(bias + n0 + 4*tx);
    #pragma unroll
    for (int i = 0; i < 4; i++) {
        float4 o;
        o.x = acc[i][0] + bv.x; o.y = acc[i][1] + bv.y;
        o.z = acc[i][2] + bv.z; o.w = acc[i][3] + bv.w;
        *(float4*)(out + (size_t)(m0 + 4*ty + i) * D + n0 + 4*tx) = o;
    }
}

// 64 q/k rows x 64 dk staged transposed into LDS [dk][row] (pad 68).
#define STAGE64(dst, srcbase)                                                 \
    {                                                                         \
        _Pragma("unroll")                                                     \
        for (int r_ = 0; r_ < 4; r_++) {                                      \
            int f_  = tid + 256 * r_;                                         \
            int rr_ = f_ >> 4;                                                \
            int cc_ = (f_ & 15) << 2;                                         \
            float4 v_ = *(const float4*)((srcbase) + (size_t)rr_ * D + cc_);  \
            dst[cc_+0][rr_] = v_.x; dst[cc_+1][rr_] = v_.y;                   \
            dst[cc_+2][rr_] = v_.z; dst[cc_+3][rr_] = v_.w;                   \
        }                                                                     \
    }

// dot[i][j] += sum_kk Aq[kk][ca+i] * Bk[kk][cb+j]  -- IDENTICAL fma order in
// every kernel that calls it (argmax / rowpass / colpass consistency).
__device__ __forceinline__ void dot64(const float (*Aq)[68], const float (*Bk)[68],
                                      int ca, int cb, float dot[4][4])
{
    #pragma unroll
    for (int kk = 0; kk < 64; kk++) {
        float4 a = *(const float4*)&Aq[kk][ca];
        float4 b = *(const float4*)&Bk[kk][cb];
        dot[0][0] += a.x*b.x; dot[0][1] += a.x*b.y; dot[0][2] += a.x*b.z; dot[0][3] += a.x*b.w;
        dot[1][0] += a.y*b.x; dot[1][1] += a.y*b.y; dot[1][2] += a.y*b.z; dot[1][3] += a.y*b.w;
        dot[2][0] += a.z*b.x; dot[2][1] += a.z*b.y; dot[2][2] += a.z*b.z; dot[2][3] += a.z*b.w;
        dot[3][0] += a.w*b.x; dot[3][1] += a.w*b.y; dot[3][2] += a.w*b.z; dot[3][3] += a.w*b.w;
    }
}

// ---------------------------------------------------------------------------
// Kernel B: per-key argmax over queries of raw scores (pre-gaussian).
// Block: one (bh, 64-key tile).  Loops all 36 q-tiles.
// Tie-break: lowest q wins (np.argmax semantics).
// ---------------------------------------------------------------------------
__global__ __launch_bounds__(256)
void argmax_kernel(const float* __restrict__ Q, const float* __restrict__ K,
                   int* __restrict__ idxout)
{
    const int bh = blockIdx.y;
    const int b = bh >> 3, h = bh & 7;
    const int kt0 = blockIdx.x * 64;
    const float* Qb = Q + (size_t)b * N * D + h * DK;
    const float* Kb = K + (size_t)b * N * D + h * DK;

    __shared__ alignas(16) float Ks[64][68];
    __shared__ alignas(16) float Qs[64][68];

    const int tx = threadIdx.x, ty = threadIdx.y;
    const int tid = ty * 16 + tx;

    STAGE64(Ks, Kb + (size_t)kt0 * D);
    __syncthreads();

    float bestv[4] = {-1e30f, -1e30f, -1e30f, -1e30f};
    int   besti[4] = {0, 0, 0, 0};

    for (int qt = 0; qt < N; qt += 64) {
        STAGE64(Qs, Qb + (size_t)qt * D);
        __syncthreads();
        float dot[4][4] = {};
        dot64(Qs, Ks, 4 * ty, 4 * tx, dot);   // dot[q_i][k_j]
        #pragma unroll
        for (int i = 0; i < 4; i++) {
            int q = qt + 4 * ty + i;
            #pragma unroll
            for (int j = 0; j < 4; j++) {
                if (dot[i][j] > bestv[j]) { bestv[j] = dot[i][j]; besti[j] = q; }
            }
        }
        __syncthreads();
    }
    // cross-ty reduce: Qs holds values, Ks holds index bits
    #pragma unroll
    for (int j = 0; j < 4; j++) {
        Qs[4 * tx + j][ty] = bestv[j];
        Ks[4 * tx + j][ty] = __int_as_float(besti[j]);
    }
    __syncthreads();
    if (tid < 64) {
        float bv = Qs[tid][0]; int bi = __float_as_int(Ks[tid][0]);
        for (int t = 1; t < 16; t++) {
            float v = Qs[tid][t]; int ii = __float_as_int(Ks[tid][t]);
            if (v > bv || (v == bv && ii < bi)) { bv = v; bi = ii; }
        }
        idxout[(size_t)bh * N + kt0 + tid] = bi;
    }
}

// ---------------------------------------------------------------------------
// Kernel C: row pass.  Online softmax over k of s=score*gk/8 per q row:
// rowmax, denom, and x0 = (sum_k e * v0[k]) / denom.
// Block: one (bh, 64-query tile).  Loops all 36 k-tiles.
// ---------------------------------------------------------------------------
__global__ __launch_bounds__(256)
void rowpass_kernel(const float* __restrict__ Q, const float* __restrict__ K,
                    const int* __restrict__ idxbuf, const float* __restrict__ value0,
                    float* __restrict__ rowmax, float* __restrict__ denom,
                    float* __restrict__ x0)
{
    const int bh = blockIdx.y;
    const int b = bh >> 3, h = bh & 7;
    const int q0 = blockIdx.x * 64;
    const float* Qb = Q + (size_t)b * N * D + h * DK;
    const float* Kb = K + (size_t)b * N * D + h * DK;

    __shared__ alignas(16) float Qs[64][68];
    __shared__ alignas(16) float Ks[64][68];
    __shared__ float F[48][48];
    __shared__ int   ixi[64], iyi[64];
    __shared__ float v0s[64];

    const int tx = threadIdx.x, ty = threadIdx.y;
    const int tid = ty * 16 + tx;

    // gaussian factor table F[a][j] = exp(-(lin[j]-a)^2 / 50)
    for (int i = tid; i < 48 * 48; i += 256) {
        int a = i / 48, j = i % 48;
        float lj = -1.0f + (2.0f / 47.0f) * (float)j;
        float dd = lj - (float)a;
        F[a][j] = expf(-dd * dd * INV2S2);
    }
    STAGE64(Qs, Qb + (size_t)q0 * D);

    int qx[4], qy[4];
    #pragma unroll
    for (int i = 0; i < 4; i++) {
        int qg = q0 + 4 * tx + i;
        qx[i] = qg % 48; qy[i] = qg / 48;
    }
    float m[4]  = {-1e30f, -1e30f, -1e30f, -1e30f};
    float l[4]  = {0.f, 0.f, 0.f, 0.f};
    float a0[4] = {0.f, 0.f, 0.f, 0.f};

    for (int kt = 0; kt < N; kt += 64) {
        STAGE64(Ks, Kb + (size_t)kt * D);
        if (tid < 64) {
            int v = idxbuf[(size_t)bh * N + kt + tid];
            ixi[tid] = v % 48; iyi[tid] = v / 48;
            v0s[tid] = value0[(size_t)b * N + kt + tid];
        }
        __syncthreads();
        float dot[4][4] = {};
        dot64(Qs, Ks, 4 * tx, 4 * ty, dot);   // dot[q_i][k_j]
        #pragma unroll
        for (int j = 0; j < 4; j++) {
            int kl = 4 * ty + j;
            int ix = ixi[kl], iy = iyi[kl];
            float v0 = v0s[kl];
            #pragma unroll
            for (int i = 0; i < 4; i++) {
                float s  = dot[i][j] * F[ix][qx[i]] * F[iy][qy[i]] * SCALE;
                float mn = fmaxf(m[i], s);
                float sc = expf(m[i] - mn);
                float e  = expf(s - mn);
                l[i]  = l[i]  * sc + e;
                a0[i] = a0[i] * sc + e * v0;
                m[i]  = mn;
            }
        }
        __syncthreads();
    }
    // merge 16 ty-partials per q (reuse Ks as scratch)
    float* red = &Ks[0][0];
    #pragma unroll
    for (int i = 0; i < 4; i++) {
        int ql = 4 * tx + i;
        red[ql * 48 + ty * 3 + 0] = m[i];
        red[ql * 48 + ty * 3 + 1] = l[i];
        red[ql * 48 + ty * 3 + 2] = a0[i];
    }
    __syncthreads();
    if (tid < 64) {
        float M = -1e30f;
        for (int t = 0; t < 16; t++) M = fmaxf(M, red[tid * 48 + t * 3]);
        float L = 0.f, A = 0.f;
        for (int t = 0; t < 16; t++) {
            float sc = expf(red[tid * 48 + t * 3] - M);
            L += red[tid * 48 + t * 3 + 1] * sc;
            A += red[tid * 48 + t * 3 + 2] * sc;
        }
        rowmax[(size_t)bh * N + q0 + tid] = M;
        denom [(size_t)bh * N + q0 + tid] = L;
        x0    [(size_t)bh * N + q0 + tid] = A / L;
    }
}

// ---------------------------------------------------------------------------
// Kernel D: column pass.  x1[k] = sum_q exp(s - rowmax[q]) * v1[q]/denom[q].
// Block: one (bh, 64-key tile).  Loops all 36 q-tiles.
// ---------------------------------------------------------------------------
__global__ __launch_bounds__(256)
void colpass_kernel(const float* __restrict__ Q, const float* __restrict__ K,
                    const int* __restrict__ idxbuf, const float* __restrict__ value1,
                    const float* __restrict__ rowmax, const float* __restrict__ denom,
                    float* __restrict__ x1)
{
    const int bh = blockIdx.y;
    const int b = bh >> 3, h = bh & 7;
    const int kt0 = blockIdx.x * 64;
    const float* Qb = Q + (size_t)b * N * D + h * DK;
    const float* Kb = K + (size_t)b * N * D + h * DK;

    __shared__ alignas(16) float Ks[64][68];
    __shared__ alignas(16) float Qs[64][68];
    __shared__ float F[48][48];
    __shared__ int   ixi[64], iyi[64];
    __shared__ float rmx[64], wv[64];
    __shared__ int   qxs[64], qys[64];

    const int tx = threadIdx.x, ty = threadIdx.y;
    const int tid = ty * 16 + tx;

    for (int i = tid; i < 48 * 48; i += 256) {
        int a = i / 48, j = i % 48;
        float lj = -1.0f + (2.0f / 47.0f) * (float)j;
        float dd = lj - (float)a;
        F[a][j] = expf(-dd * dd * INV2S2);
    }
    STAGE64(Ks, Kb + (size_t)kt0 * D);
    if (tid < 64) {
        int v = idxbuf[(size_t)bh * N + kt0 + tid];
        ixi[tid] = v % 48; iyi[tid] = v / 48;
    }
    __syncthreads();

    float acc[4] = {0.f, 0.f, 0.f, 0.f};

    for (int qt = 0; qt < N; qt += 64) {
        STAGE64(Qs, Qb + (size_t)qt * D);
        if (tid < 64) {
            int qg = qt + tid;
            rmx[tid] = rowmax[(size_t)bh * N + qg];
            wv[tid]  = value1[(size_t)b * N + qg] / denom[(size_t)bh * N + qg];
            qxs[tid] = qg % 48; qys[tid] = qg / 48;
        }
        __syncthreads();
        float dot[4][4] = {};
        dot64(Qs, Ks, 4 * ty, 4 * tx, dot);   // dot[q_i][k_j]  (same fma order as rowpass)
        #pragma unroll
        for (int i = 0; i < 4; i++) {
            int ql = 4 * ty + i;
            float rm = rmx[ql], w = wv[ql];
            int qxv = qxs[ql], qyv = qys[ql];
            #pragma unroll
            for (int j = 0; j < 4; j++) {
                int kl = 4 * tx + j;
                float s = dot[i][j] * F[ixi[kl]][qxv] * F[iyi[kl]][qyv] * SCALE;
                float e = expf(s - rm);
                acc[j] += e * w;
            }
        }
        __syncthreads();
    }
    // sum 16 ty-partials per k (reuse Qs)
    float* red = &Qs[0][0];
    #pragma unroll
    for (int j = 0; j < 4; j++) red[(4 * tx + j) * 16 + ty] = acc[j];
    __syncthreads();
    if (tid < 64) {
        float sum = 0.f;
        for (int t = 0; t < 16; t++) sum += red[tid * 16 + t];
        x1[(size_t)bh * N + kt0 + tid] = sum;
    }
}

// ---------------------------------------------------------------------------
// Kernel E: out[b,q,k] = (1/8) * sum_h x0[b,h,q] * x1[b,h,k]
// ---------------------------------------------------------------------------
__global__ __launch_bounds__(256)
void outer_kernel(const float* __restrict__ x0, const float* __restrict__ x1,
                  float* __restrict__ out)
{
    const int b = blockIdx.z;
    const int q0 = blockIdx.y * 16, k0 = blockIdx.x * 16;
    __shared__ float x0s[8][16];
    __shared__ float x1s[8][16];
    const int tx = threadIdx.x, ty = threadIdx.y;
    const int tid = ty * 16 + tx;
    if (tid < 128) {
        int hh = tid >> 4, i = tid & 15;
        x0s[hh][i] = x0[(size_t)(b * 8 + hh) * N + q0 + i];
    } else {
        int t = tid - 128;
        int hh = t >> 4, i = t & 15;
        x1s[hh][i] = x1[(size_t)(b * 8 + hh) * N + k0 + i];
    }
    __syncthreads();
    float acc = 0.f;
    #pragma unroll
    for (int hh = 0; hh < 8; hh++) acc += x0s[hh][ty] * x1s[hh][tx];
    out[(size_t)b * N * N + (size_t)(q0 + ty) * N + (k0 + tx)] = 0.125f * acc;
}

} // namespace

extern "C" void kernel_launch(void* const* d_in, const int* in_sizes, int n_in,
                              void* d_out, int out_size, void* d_ws, size_t ws_size,
                              hipStream_t stream) {
    const float* qin = (const float*)d_in[0];
    const float* kin = (const float*)d_in[1];
    const float* v0  = (const float*)d_in[2];
    const float* v1  = (const float*)d_in[3];
    const float* Wq  = (const float*)d_in[4];
    const float* bq  = (const float*)d_in[5];
    const float* Wk  = (const float*)d_in[6];
    const float* bk  = (const float*)d_in[7];
    float* out = (float*)d_out;

    // Q/K projections live in d_out scratch space (4.7M floats of the 10.6M
    // output buffer); kernel E fully overwrites d_out afterwards.  Small
    // per-row/col stats live in d_ws (~0.9 MB).
    float* Qb = out;
    float* Kb = Qb + (size_t)B * N * D;

    int*   idxb = (int*)d_ws;
    float* rmx  = (float*)(idxb + (size_t)BH * N);
    float* den  = rmx + (size_t)BH * N;
    float* x0b  = den + (size_t)BH * N;
    float* x1b  = x0b + (size_t)BH * N;

    dim3 blk(16, 16);
    proj_kernel   <<<dim3(8, 72, 2),    blk, 0, stream>>>(qin, kin, Wq, bq, Wk, bk, Qb, Kb);
    argmax_kernel <<<dim3(36, 16),      blk, 0, stream>>>(Qb, Kb, idxb);
    rowpass_kernel<<<dim3(36, 16),      blk, 0, stream>>>(Qb, Kb, idxb, v0, rmx, den, x0b);
    colpass_kernel<<<dim3(36, 16),      blk, 0, stream>>>(Qb, Kb, idxb, v1, rmx, den, x1b);
    outer_kernel  <<<dim3(144, 144, 2), blk, 0, stream>>>(x0b, x1b, out);
}

// Round 2
// 336.231 us; speedup vs baseline: 2.7283x; 2.7283x over previous
//
#include <hip/hip_runtime.h>
#include <cstddef>
#include <cstdint>

namespace {

constexpr int S = 48;
constexpr int N = S * S;        // 2304 positions
constexpr int D = 512;          // d_model
constexpr int DK = 64;          // head dim
constexpr int B = 2;
constexpr int BH = 16;          // b*heads
constexpr float SCALE = 0.125f;     // 1/sqrt(DK)
constexpr float INV2S2 = 0.02f;     // 1/(2*sigma^2), sigma=5

typedef __attribute__((ext_vector_type(8))) short short8;
typedef __attribute__((ext_vector_type(8))) unsigned short ushort8v;
typedef __attribute__((ext_vector_type(4))) float f32x4;

#define MFMA(a, b, c) __builtin_amdgcn_mfma_f32_16x16x32_bf16((a), (b), (c), 0, 0, 0)

// 3-way bf16 split: x ~= s1 + s2 + s3 (each RNE bf16), residual ~2^-26|x|
__device__ __forceinline__ void split3(float x, ushort& u1, ushort& u2, ushort& u3)
{
    uint b1 = __float_as_uint(x);
    uint r1 = (b1 + (0x7FFFu + ((b1 >> 16) & 1u))) & 0xFFFF0000u;
    u1 = (ushort)(r1 >> 16);
    float d1 = x - __uint_as_float(r1);                 // exact
    uint b2 = __float_as_uint(d1);
    uint r2 = (b2 + (0x7FFFu + ((b2 >> 16) & 1u))) & 0xFFFF0000u;
    u2 = (ushort)(r2 >> 16);
    float d2 = d1 - __uint_as_float(r2);                // exact
    uint b3 = __float_as_uint(d2);
    u3 = (ushort)((b3 + (0x7FFFu + ((b3 >> 16) & 1u))) >> 16);
}

// Copy a 64x64 ushort tile global -> LDS [64][72] (16B chunks, coalesced).
__device__ __forceinline__ void stage_tile(const ushort* __restrict__ g,
                                           ushort (*L)[72], int tid)
{
    #pragma unroll
    for (int it = 0; it < 2; it++) {
        int f = tid + 256 * it;
        int row = f >> 3, c8 = (f & 7) * 8;
        *(ushort8v*)&L[row][c8] = *(const ushort8v*)&g[(size_t)row * 64 + c8];
    }
}

__device__ __forceinline__ short8 frag(const ushort (*L)[72], int row, int k)
{
    return *(const short8*)&L[row][k];
}

// ---------------------------------------------------------------------------
// Kernel A: fused Q/K projection -> 3-way bf16 split arrays, per-head layout
// [bh][n][64].  out = X @ W^T + bias.  64x64 tile, 256 threads, 4x4/thread.
// ---------------------------------------------------------------------------
__global__ __launch_bounds__(256)
void proj_kernel(const float* __restrict__ qin, const float* __restrict__ kin,
                 const float* __restrict__ Wq, const float* __restrict__ bq,
                 const float* __restrict__ Wk, const float* __restrict__ bk,
                 ushort* __restrict__ q1, ushort* __restrict__ q2, ushort* __restrict__ q3,
                 ushort* __restrict__ k1, ushort* __restrict__ k2, ushort* __restrict__ k3)
{
    const float* X; const float* W; const float* bias;
    ushort *O1, *O2, *O3;
    if (blockIdx.z == 0) { X = qin; W = Wq; bias = bq; O1 = q1; O2 = q2; O3 = q3; }
    else                 { X = kin; W = Wk; bias = bk; O1 = k1; O2 = k2; O3 = k3; }

    __shared__ alignas(16) float As[16][68];
    __shared__ alignas(16) float Ws[16][68];

    const int tx = threadIdx.x, ty = threadIdx.y;
    const int tid = ty * 16 + tx;
    const int m0 = blockIdx.y * 64;           // position-row tile (0..71)
    const int hsel = blockIdx.x;              // head = n-tile (64 cols = 1 head)
    const int n0 = hsel * 64;
    const int lr = tid >> 2;
    const int lc = (tid & 3) << 2;

    float acc[4][4] = {};

    for (int k0 = 0; k0 < D; k0 += 16) {
        float4 av = *(const float4*)(X + (size_t)(m0 + lr) * D + k0 + lc);
        float4 wv = *(const float4*)(W + (size_t)(n0 + lr) * D + k0 + lc);
        As[lc+0][lr] = av.x; As[lc+1][lr] = av.y; As[lc+2][lr] = av.z; As[lc+3][lr] = av.w;
        Ws[lc+0][lr] = wv.x; Ws[lc+1][lr] = wv.y; Ws[lc+2][lr] = wv.z; Ws[lc+3][lr] = wv.w;
        __syncthreads();
        #pragma unroll
        for (int kk = 0; kk < 16; kk++) {
            float4 a  = *(const float4*)&As[kk][4*ty];
            float4 w4 = *(const float4*)&Ws[kk][4*tx];
            acc[0][0] += a.x*w4.x; acc[0][1] += a.x*w4.y; acc[0][2] += a.x*w4.z; acc[0][3] += a.x*w4.w;
            acc[1][0] += a.y*w4.x; acc[1][1] += a.y*w4.y; acc[1][2] += a.y*w4.z; acc[1][3] += a.y*w4.w;
            acc[2][0] += a.z*w4.x; acc[2][1] += a.z*w4.y; acc[2][2] += a.z*w4.z; acc[2][3] += a.z*w4.w;
            acc[3][0] += a.w*w4.x; acc[3][1] += a.w*w4.y; acc[3][2] += a.w*w4.z; acc[3][3] += a.w*w4.w;
        }
        __syncthreads();
    }
    float4 bv = *(const float4*)(bias + n0 + 4*tx);
    const int b = blockIdx.y / 36;
    #pragma unroll
    for (int i = 0; i < 4; i++) {
        int gm = m0 + 4*ty + i;
        int npos = gm - b * N;
        float4 o;
        o.x = acc[i][0] + bv.x; o.y = acc[i][1] + bv.y;
        o.z = acc[i][2] + bv.z; o.w = acc[i][3] + bv.w;
        ushort4 a1, a2, a3;
        split3(o.x, a1.x, a2.x, a3.x);
        split3(o.y, a1.y, a2.y, a3.y);
        split3(o.z, a1.z, a2.z, a3.z);
        split3(o.w, a1.w, a2.w, a3.w);
        size_t dst = ((size_t)(b * 8 + hsel) * N + npos) * 64 + 4 * tx;
        *(ushort4*)&O1[dst] = a1;
        *(ushort4*)&O2[dst] = a2;
        *(ushort4*)&O3[dst] = a3;
    }
}

// ---------------------------------------------------------------------------
// Kernel B: per-key argmax over queries of raw scores.  3-split, 6 MFMA
// products -> dot error ~ fp32 noise level.  Block: 64 keys; loops q-tiles.
// Waves own 32key x 32q (2x2 of 16x16).  Tie-break: lowest q.
// ---------------------------------------------------------------------------
__global__ __launch_bounds__(256)
void argmax_kernel(const ushort* __restrict__ Q1, const ushort* __restrict__ Q2,
                   const ushort* __restrict__ Q3, const ushort* __restrict__ K1,
                   const ushort* __restrict__ K2, const ushort* __restrict__ K3,
                   int* __restrict__ idxout)
{
    const int bh = blockIdx.y;
    const int kt0 = blockIdx.x * 64;
    const size_t hb = (size_t)bh * N;

    __shared__ alignas(16) ushort Ks[3][64][72];
    __shared__ alignas(16) ushort Qs[3][64][72];
    __shared__ float redv[2][64];
    __shared__ int   redq[2][64];

    const int tid = threadIdx.x;
    const int lane = tid & 63, w = tid >> 6;
    const int wk = w >> 1, wq = w & 1;
    const int lg = lane >> 4, ln = lane & 15;

    stage_tile(K1 + (hb + kt0) * 64, Ks[0], tid);
    stage_tile(K2 + (hb + kt0) * 64, Ks[1], tid);
    stage_tile(K3 + (hb + kt0) * 64, Ks[2], tid);
    __syncthreads();

    short8 A[3][2][2];                   // [comp][mt][chunk]
    #pragma unroll
    for (int mt = 0; mt < 2; mt++)
        #pragma unroll
        for (int c = 0; c < 2; c++) {
            int row = 32 * wk + 16 * mt + ln, k = 32 * c + 8 * lg;
            A[0][mt][c] = frag(Ks[0], row, k);
            A[1][mt][c] = frag(Ks[1], row, k);
            A[2][mt][c] = frag(Ks[2], row, k);
        }

    float bestv[2][4];
    int   bestq[2][4];
    #pragma unroll
    for (int mt = 0; mt < 2; mt++)
        #pragma unroll
        for (int r = 0; r < 4; r++) { bestv[mt][r] = -3e38f; bestq[mt][r] = 0; }

    for (int qt = 0; qt < N; qt += 64) {
        __syncthreads();
        stage_tile(Q1 + (hb + qt) * 64, Qs[0], tid);
        stage_tile(Q2 + (hb + qt) * 64, Qs[1], tid);
        stage_tile(Q3 + (hb + qt) * 64, Qs[2], tid);
        __syncthreads();
        #pragma unroll
        for (int nt = 0; nt < 2; nt++) {
            short8 Bv0[2], Bv1[2], Bv2[2];
            #pragma unroll
            for (int c = 0; c < 2; c++) {
                int row = 32 * wq + 16 * nt + ln, k = 32 * c + 8 * lg;
                Bv0[c] = frag(Qs[0], row, k);
                Bv1[c] = frag(Qs[1], row, k);
                Bv2[c] = frag(Qs[2], row, k);
            }
            #pragma unroll
            for (int mt = 0; mt < 2; mt++) {
                f32x4 acc = {0.f, 0.f, 0.f, 0.f};
                acc = MFMA(A[0][mt][0], Bv0[0], acc);
                acc = MFMA(A[0][mt][1], Bv0[1], acc);
                acc = MFMA(A[0][mt][0], Bv1[0], acc);
                acc = MFMA(A[0][mt][1], Bv1[1], acc);
                acc = MFMA(A[1][mt][0], Bv0[0], acc);
                acc = MFMA(A[1][mt][1], Bv0[1], acc);
                acc = MFMA(A[0][mt][0], Bv2[0], acc);
                acc = MFMA(A[0][mt][1], Bv2[1], acc);
                acc = MFMA(A[1][mt][0], Bv1[0], acc);
                acc = MFMA(A[1][mt][1], Bv1[1], acc);
                acc = MFMA(A[2][mt][0], Bv0[0], acc);
                acc = MFMA(A[2][mt][1], Bv0[1], acc);
                int q = qt + 32 * wq + 16 * nt + ln;
                #pragma unroll
                for (int r = 0; r < 4; r++)
                    if (acc[r] > bestv[mt][r]) { bestv[mt][r] = acc[r]; bestq[mt][r] = q; }
            }
        }
    }
    #pragma unroll
    for (int d = 1; d < 16; d <<= 1) {
        #pragma unroll
        for (int mt = 0; mt < 2; mt++)
            #pragma unroll
            for (int r = 0; r < 4; r++) {
                float ov = __shfl_xor(bestv[mt][r], d);
                int   oq = __shfl_xor(bestq[mt][r], d);
                if (ov > bestv[mt][r] || (ov == bestv[mt][r] && oq < bestq[mt][r])) {
                    bestv[mt][r] = ov; bestq[mt][r] = oq;
                }
            }
    }
    if (ln == 0) {
        #pragma unroll
        for (int mt = 0; mt < 2; mt++)
            #pragma unroll
            for (int r = 0; r < 4; r++) {
                int key = 32 * wk + 16 * mt + 4 * lg + r;
                redv[wq][key] = bestv[mt][r];
                redq[wq][key] = bestq[mt][r];
            }
    }
    __syncthreads();
    if (tid < 64) {
        float va = redv[0][tid], vb = redv[1][tid];
        int   qa = redq[0][tid], qb = redq[1][tid];
        int bi = (vb > va || (vb == va && qb < qa)) ? qb : qa;
        idxout[hb + kt0 + tid] = bi;
    }
}

// ---------------------------------------------------------------------------
// Kernel C: row pass (online softmax over k): rowmax, denom, x0.
// Block: 64 queries; loops k-tiles.  2-split, 3 MFMA products.
// ---------------------------------------------------------------------------
__global__ __launch_bounds__(256)
void rowpass_kernel(const ushort* __restrict__ Q1, const ushort* __restrict__ Q2,
                    const ushort* __restrict__ K1, const ushort* __restrict__ K2,
                    const int* __restrict__ idxbuf, const float* __restrict__ value0,
                    float* __restrict__ rowmax, float* __restrict__ denomo,
                    float* __restrict__ x0o)
{
    const int bh = blockIdx.y, b = bh >> 3;
    const int q0 = blockIdx.x * 64;
    const size_t hb = (size_t)bh * N;

    __shared__ alignas(16) ushort Qs[2][64][72];
    __shared__ alignas(16) ushort Ks[2][64][72];
    __shared__ float F[48][48];
    __shared__ int ixi[64], iyi[64];
    __shared__ float v0s[64];
    __shared__ float red[64][2][3];

    const int tid = threadIdx.x;
    const int lane = tid & 63, w = tid >> 6;
    const int wk = w >> 1, wq = w & 1;
    const int lg = lane >> 4, ln = lane & 15;

    for (int i = tid; i < 48 * 48; i += 256) {
        int a = i / 48, j = i % 48;
        float lj = -1.0f + (2.0f / 47.0f) * (float)j;
        float dd = lj - (float)a;
        F[a][j] = __expf(-dd * dd * INV2S2);
    }
    stage_tile(Q1 + (hb + q0) * 64, Qs[0], tid);
    stage_tile(Q2 + (hb + q0) * 64, Qs[1], tid);
    __syncthreads();

    short8 Bq[2][2][2];                  // [comp][nt][chunk]
    int qx_[2], qy_[2];
    #pragma unroll
    for (int nt = 0; nt < 2; nt++) {
        #pragma unroll
        for (int c = 0; c < 2; c++) {
            int row = 32 * wq + 16 * nt + ln, k = 32 * c + 8 * lg;
            Bq[0][nt][c] = frag(Qs[0], row, k);
            Bq[1][nt][c] = frag(Qs[1], row, k);
        }
        int qq = q0 + 32 * wq + 16 * nt + ln;
        qx_[nt] = qq % 48; qy_[nt] = qq / 48;
    }

    float m[2] = {-1e30f, -1e30f}, l[2] = {0.f, 0.f}, a0[2] = {0.f, 0.f};

    for (int kt = 0; kt < N; kt += 64) {
        __syncthreads();
        stage_tile(K1 + (hb + kt) * 64, Ks[0], tid);
        stage_tile(K2 + (hb + kt) * 64, Ks[1], tid);
        if (tid < 64) {
            int v = idxbuf[hb + kt + tid];
            ixi[tid] = v % 48; iyi[tid] = v / 48;
            v0s[tid] = value0[(size_t)b * N + kt + tid];
        }
        __syncthreads();
        short8 A[2][2][2];               // [comp][mt][chunk]
        #pragma unroll
        for (int mt = 0; mt < 2; mt++)
            #pragma unroll
            for (int c = 0; c < 2; c++) {
                int row = 32 * wk + 16 * mt + ln, k = 32 * c + 8 * lg;
                A[0][mt][c] = frag(Ks[0], row, k);
                A[1][mt][c] = frag(Ks[1], row, k);
            }
        #pragma unroll
        for (int nt = 0; nt < 2; nt++) {
            float s[2][4];
            #pragma unroll
            for (int mt = 0; mt < 2; mt++) {
                f32x4 acc = {0.f, 0.f, 0.f, 0.f};
                acc = MFMA(A[0][mt][0], Bq[0][nt][0], acc);
                acc = MFMA(A[0][mt][1], Bq[0][nt][1], acc);
                acc = MFMA(A[0][mt][0], Bq[1][nt][0], acc);
                acc = MFMA(A[0][mt][1], Bq[1][nt][1], acc);
                acc = MFMA(A[1][mt][0], Bq[0][nt][0], acc);
                acc = MFMA(A[1][mt][1], Bq[0][nt][1], acc);
                #pragma unroll
                for (int r = 0; r < 4; r++) {
                    int kl = 32 * wk + 16 * mt + 4 * lg + r;
                    s[mt][r] = acc[r] * F[ixi[kl]][qx_[nt]] * F[iyi[kl]][qy_[nt]] * SCALE;
                }
            }
            float tmax = fmaxf(fmaxf(fmaxf(s[0][0], s[0][1]), fmaxf(s[0][2], s[0][3])),
                               fmaxf(fmaxf(s[1][0], s[1][1]), fmaxf(s[1][2], s[1][3])));
            float mn = fmaxf(m[nt], tmax);
            float sc = __expf(m[nt] - mn);
            float es = 0.f, as = 0.f;
            #pragma unroll
            for (int mt = 0; mt < 2; mt++)
                #pragma unroll
                for (int r = 0; r < 4; r++) {
                    float e = __expf(s[mt][r] - mn);
                    es += e;
                    as += e * v0s[32 * wk + 16 * mt + 4 * lg + r];
                }
            l[nt] = l[nt] * sc + es;
            a0[nt] = a0[nt] * sc + as;
            m[nt] = mn;
        }
    }
    // merge across lane-groups (keys) within the wave
    #pragma unroll
    for (int d = 16; d < 64; d <<= 1) {
        #pragma unroll
        for (int nt = 0; nt < 2; nt++) {
            float om = __shfl_xor(m[nt], d);
            float ol = __shfl_xor(l[nt], d);
            float oa = __shfl_xor(a0[nt], d);
            float M = fmaxf(m[nt], om);
            float s1 = __expf(m[nt] - M), s2 = __expf(om - M);
            l[nt] = l[nt] * s1 + ol * s2;
            a0[nt] = a0[nt] * s1 + oa * s2;
            m[nt] = M;
        }
    }
    if (lane < 16) {
        #pragma unroll
        for (int nt = 0; nt < 2; nt++) {
            int ql = 32 * wq + 16 * nt + ln;
            red[ql][wk][0] = m[nt];
            red[ql][wk][1] = l[nt];
            red[ql][wk][2] = a0[nt];
        }
    }
    __syncthreads();
    if (tid < 64) {
        float M = red[tid][0][0], L = red[tid][0][1], Aa = red[tid][0][2];
        float m2 = red[tid][1][0], l2 = red[tid][1][1], a2 = red[tid][1][2];
        float Mn = fmaxf(M, m2);
        float s1 = __expf(M - Mn), s2 = __expf(m2 - Mn);
        L = L * s1 + l2 * s2; Aa = Aa * s1 + a2 * s2;
        rowmax[hb + q0 + tid] = Mn;
        denomo[hb + q0 + tid] = L;
        x0o[hb + q0 + tid] = Aa / L;
    }
}

// ---------------------------------------------------------------------------
// Kernel D: column pass.  x1[k] = sum_q exp(s - rowmax[q]) * v1[q]/denom[q].
// Block: 64 keys; loops q-tiles.  Same 3-product MFMA order as rowpass.
// ---------------------------------------------------------------------------
__global__ __launch_bounds__(256)
void colpass_kernel(const ushort* __restrict__ Q1, const ushort* __restrict__ Q2,
                    const ushort* __restrict__ K1, const ushort* __restrict__ K2,
                    const int* __restrict__ idxbuf, const float* __restrict__ value1,
                    const float* __restrict__ rowmax, const float* __restrict__ denomo,
                    float* __restrict__ x1o)
{
    const int bh = blockIdx.y, b = bh >> 3;
    const int kt0 = blockIdx.x * 64;
    const size_t hb = (size_t)bh * N;

    __shared__ alignas(16) ushort Ks[2][64][72];
    __shared__ alignas(16) ushort Qs[2][64][72];
    __shared__ float F[48][48];
    __shared__ int ixi[64], iyi[64];
    __shared__ float rmxs[64], wvs[64];
    __shared__ int qxs[64], qys[64];
    __shared__ float redx[2][64];

    const int tid = threadIdx.x;
    const int lane = tid & 63, w = tid >> 6;
    const int wk = w >> 1, wq = w & 1;
    const int lg = lane >> 4, ln = lane & 15;

    for (int i = tid; i < 48 * 48; i += 256) {
        int a = i / 48, j = i % 48;
        float lj = -1.0f + (2.0f / 47.0f) * (float)j;
        float dd = lj - (float)a;
        F[a][j] = __expf(-dd * dd * INV2S2);
    }
    stage_tile(K1 + (hb + kt0) * 64, Ks[0], tid);
    stage_tile(K2 + (hb + kt0) * 64, Ks[1], tid);
    if (tid < 64) {
        int v = idxbuf[hb + kt0 + tid];
        ixi[tid] = v % 48; iyi[tid] = v / 48;
    }
    __syncthreads();

    short8 A[2][2][2];
    #pragma unroll
    for (int mt = 0; mt < 2; mt++)
        #pragma unroll
        for (int c = 0; c < 2; c++) {
            int row = 32 * wk + 16 * mt + ln, k = 32 * c + 8 * lg;
            A[0][mt][c] = frag(Ks[0], row, k);
            A[1][mt][c] = frag(Ks[1], row, k);
        }
    int ixr[2][4], iyr[2][4];
    #pragma unroll
    for (int mt = 0; mt < 2; mt++)
        #pragma unroll
        for (int r = 0; r < 4; r++) {
            int kl = 32 * wk + 16 * mt + 4 * lg + r;
            ixr[mt][r] = ixi[kl]; iyr[mt][r] = iyi[kl];
        }

    float acc1[2][4] = {};

    for (int qt = 0; qt < N; qt += 64) {
        __syncthreads();
        stage_tile(Q1 + (hb + qt) * 64, Qs[0], tid);
        stage_tile(Q2 + (hb + qt) * 64, Qs[1], tid);
        if (tid < 64) {
            int qg = qt + tid;
            rmxs[tid] = rowmax[hb + qg];
            wvs[tid] = value1[(size_t)b * N + qg] / denomo[hb + qg];
            qxs[tid] = qg % 48; qys[tid] = qg / 48;
        }
        __syncthreads();
        #pragma unroll
        for (int nt = 0; nt < 2; nt++) {
            short8 Bv0[2], Bv1[2];
            #pragma unroll
            for (int c = 0; c < 2; c++) {
                int row = 32 * wq + 16 * nt + ln, k = 32 * c + 8 * lg;
                Bv0[c] = frag(Qs[0], row, k);
                Bv1[c] = frag(Qs[1], row, k);
            }
            int qi = 32 * wq + 16 * nt + ln;
            int qx = qxs[qi], qy = qys[qi];
            float rm = rmxs[qi], wq_ = wvs[qi];
            #pragma unroll
            for (int mt = 0; mt < 2; mt++) {
                f32x4 acc = {0.f, 0.f, 0.f, 0.f};
                acc = MFMA(A[0][mt][0], Bv0[0], acc);
                acc = MFMA(A[0][mt][1], Bv0[1], acc);
                acc = MFMA(A[0][mt][0], Bv1[0], acc);
                acc = MFMA(A[0][mt][1], Bv1[1], acc);
                acc = MFMA(A[1][mt][0], Bv0[0], acc);
                acc = MFMA(A[1][mt][1], Bv0[1], acc);
                #pragma unroll
                for (int r = 0; r < 4; r++) {
                    float s = acc[r] * F[ixr[mt][r]][qx] * F[iyr[mt][r]][qy] * SCALE;
                    acc1[mt][r] += __expf(s - rm) * wq_;
                }
            }
        }
    }
    #pragma unroll
    for (int d = 1; d < 16; d <<= 1)
        #pragma unroll
        for (int mt = 0; mt < 2; mt++)
            #pragma unroll
            for (int r = 0; r < 4; r++)
                acc1[mt][r] += __shfl_xor(acc1[mt][r], d);
    if (ln == 0) {
        #pragma unroll
        for (int mt = 0; mt < 2; mt++)
            #pragma unroll
            for (int r = 0; r < 4; r++)
                redx[wq][32 * wk + 16 * mt + 4 * lg + r] = acc1[mt][r];
    }
    __syncthreads();
    if (tid < 64)
        x1o[hb + kt0 + tid] = redx[0][tid] + redx[1][tid];
}

// ---------------------------------------------------------------------------
// Kernel E: out[b,q,k] = (1/8) * sum_h x0[b,h,q] * x1[b,h,k]   (float4 stores)
// ---------------------------------------------------------------------------
__global__ __launch_bounds__(256)
void outer_kernel(const float* __restrict__ x0, const float* __restrict__ x1,
                  float* __restrict__ out)
{
    const int b = blockIdx.z;
    const int q0 = blockIdx.y * 32, k0 = blockIdx.x * 32;
    __shared__ float x0s[8][32];
    __shared__ float x1s[8][32];
    const int tid = threadIdx.x;
    {
        int hh = tid >> 5, i = tid & 31;
        x0s[hh][i] = x0[(size_t)(b * 8 + hh) * N + q0 + i];
        x1s[hh][i] = x1[(size_t)(b * 8 + hh) * N + k0 + i];
    }
    __syncthreads();
    const int row = tid >> 3, c4 = (tid & 7) * 4;
    float4 a = {0.f, 0.f, 0.f, 0.f};
    #pragma unroll
    for (int hh = 0; hh < 8; hh++) {
        float s = x0s[hh][row];
        a.x += s * x1s[hh][c4 + 0];
        a.y += s * x1s[hh][c4 + 1];
        a.z += s * x1s[hh][c4 + 2];
        a.w += s * x1s[hh][c4 + 3];
    }
    a.x *= 0.125f; a.y *= 0.125f; a.z *= 0.125f; a.w *= 0.125f;
    *(float4*)(out + (size_t)b * N * N + (size_t)(q0 + row) * N + k0 + c4) = a;
}

} // namespace

extern "C" void kernel_launch(void* const* d_in, const int* in_sizes, int n_in,
                              void* d_out, int out_size, void* d_ws, size_t ws_size,
                              hipStream_t stream) {
    const float* qin = (const float*)d_in[0];
    const float* kin = (const float*)d_in[1];
    const float* v0  = (const float*)d_in[2];
    const float* v1  = (const float*)d_in[3];
    const float* Wq  = (const float*)d_in[4];
    const float* bq  = (const float*)d_in[5];
    const float* Wk  = (const float*)d_in[6];
    const float* bk  = (const float*)d_in[7];
    float* out = (float*)d_out;

    // 3-way bf16-split Q/K live in d_out scratch (6 arrays x 4.72 MB = 28.3 MB
    // of the 42.5 MB output buffer); outer_kernel fully overwrites d_out last.
    const size_t ARR = (size_t)BH * N * DK;   // 2359296 elements per split array
    ushort* Q1 = (ushort*)d_out;
    ushort* Q2 = Q1 + ARR;
    ushort* Q3 = Q2 + ARR;
    ushort* K1 = Q3 + ARR;
    ushort* K2 = K1 + ARR;
    ushort* K3 = K2 + ARR;

    int*   idxb = (int*)d_ws;
    float* rmx  = (float*)(idxb + (size_t)BH * N);
    float* den  = rmx + (size_t)BH * N;
    float* x0b  = den + (size_t)BH * N;
    float* x1b  = x0b + (size_t)BH * N;

    proj_kernel   <<<dim3(8, 72, 2),  dim3(16, 16), 0, stream>>>(qin, kin, Wq, bq, Wk, bk,
                                                                 Q1, Q2, Q3, K1, K2, K3);
    argmax_kernel <<<dim3(36, 16),    dim3(256),    0, stream>>>(Q1, Q2, Q3, K1, K2, K3, idxb);
    rowpass_kernel<<<dim3(36, 16),    dim3(256),    0, stream>>>(Q1, Q2, K1, K2, idxb, v0,
                                                                 rmx, den, x0b);
    colpass_kernel<<<dim3(36, 16),    dim3(256),    0, stream>>>(Q1, Q2, K1, K2, idxb, v1,
                                                                 rmx, den, x1b);
    outer_kernel  <<<dim3(72, 72, 2), dim3(256),    0, stream>>>(x0b, x1b, out);
}